// Round 1
// baseline (338.262 us; speedup 1.0000x reference)
//
#include <hip/hip_runtime.h>
#include <cstdint>
#include <cstddef>

#define HIDDEN   2880
#define QKV_N    5120      // (64 + 2*8)*64
#define OPROJ_K  4096      // 64*64
#define NTOK     2048
#define WIN      128
#define SM_SCALE 0.125f

typedef _Float16 half8  __attribute__((ext_vector_type(8)));
typedef _Float16 half4v __attribute__((ext_vector_type(4)));
typedef float    f32x4  __attribute__((ext_vector_type(4)));

__device__ __forceinline__ void gload16(const void* g, void* l) {
  // async global->LDS, 16B per lane; LDS dest = wave-uniform base + lane*16
  __builtin_amdgcn_global_load_lds((__attribute__((address_space(1))) void*)g,
                                   (__attribute__((address_space(3))) void*)l,
                                   16, 0, 0);
}

__device__ __forceinline__ _Float16 f2h(float f) { return (_Float16)f; }

// ================= merged prep kernel =================
// blocks [0, NB_T0)      : cast+transpose w_qkv -> wtq[5120][2880] f16 (64x64 tiles)
// blocks [.., +NB_T1)    : cast+transpose w_o   -> wto[2944][4096] f16 (rows>=2880 zero)
// blocks [.., +NTOK)     : rmsnorm row
// blocks [.., +NB_ROPE)  : YaRN rope table
#define NB_T0  (80 * 45)
#define NB_T1  (46 * 64)
#define NB_ROPE 256

__device__ __forceinline__ void cast_transpose64(const float* __restrict__ W,
                                                 _Float16* __restrict__ Wt,
                                                 int K, int N, int n0, int k0,
                                                 float* tile /*64x65*/) {
  int t = threadIdx.x;
  #pragma unroll
  for (int p = 0; p < 16; ++p) {
    int r = p * 4 + (t >> 6), cc = t & 63;     // r = k-local, cc = n-local
    float vv = 0.f;
    if (n0 + cc < N) vv = W[(size_t)(k0 + r) * N + n0 + cc];
    tile[r * 65 + cc] = vv;
  }
  __syncthreads();
  #pragma unroll
  for (int p = 0; p < 2; ++p) {
    int idx = p * 256 + t;
    int r = idx >> 3, ch = (idx & 7) * 8;      // r = n-local, ch = k-local
    half8 h;
    #pragma unroll
    for (int u = 0; u < 8; ++u) h[u] = (_Float16)tile[(ch + u) * 65 + r];
    *(half8*)&Wt[(size_t)(n0 + r) * K + k0 + ch] = h;
  }
}

__global__ __launch_bounds__(256) void prep_kernel(const float* __restrict__ x,
                                                   const float* __restrict__ scale,
                                                   const float* __restrict__ w_qkv,
                                                   const float* __restrict__ w_o,
                                                   _Float16* __restrict__ a_h,
                                                   _Float16* __restrict__ wtq,
                                                   _Float16* __restrict__ wto,
                                                   float2* __restrict__ tab) {
  __shared__ float smem[64 * 65];
  int b = blockIdx.x, t = threadIdx.x;
  if (b < NB_T0) {
    cast_transpose64(w_qkv, wtq, HIDDEN, QKV_N, (b % 80) * 64, (b / 80) * 64, smem);
    return;
  }
  b -= NB_T0;
  if (b < NB_T1) {
    cast_transpose64(w_o, wto, OPROJ_K, HIDDEN, (b % 46) * 64, (b / 46) * 64, smem);
    return;
  }
  b -= NB_T1;
  if (b < NTOK) {
    // ---- RMSNorm row b: fp32 -> f16 normalized*scale ----
    int row = b;
    const float4* xr = (const float4*)(x + (size_t)row * HIDDEN);
    const float4* sc = (const float4*)scale;
    float4 v0 = xr[t];
    float4 v1 = xr[t + 256];
    float4 v2 = (t < 208) ? xr[t + 512] : make_float4(0.f, 0.f, 0.f, 0.f);
    float ss = v0.x*v0.x + v0.y*v0.y + v0.z*v0.z + v0.w*v0.w
             + v1.x*v1.x + v1.y*v1.y + v1.z*v1.z + v1.w*v1.w
             + v2.x*v2.x + v2.y*v2.y + v2.z*v2.z + v2.w*v2.w;
    #pragma unroll
    for (int m = 1; m < 64; m <<= 1) ss += __shfl_xor(ss, m, 64);
    if ((t & 63) == 0) smem[t >> 6] = ss;
    __syncthreads();
    float inv = 1.0f / sqrtf((smem[0] + smem[1] + smem[2] + smem[3]) * (1.0f / HIDDEN) + 1e-5f);
    _Float16* orow = a_h + (size_t)row * HIDDEN;
    auto store4 = [&](int c4, const float4& v, const float4& s) {
      half4v h;
      h[0] = f2h(v.x * inv * s.x); h[1] = f2h(v.y * inv * s.y);
      h[2] = f2h(v.z * inv * s.z); h[3] = f2h(v.w * inv * s.w);
      *(half4v*)(orow + (size_t)c4 * 4) = h;
    };
    store4(t, v0, sc[t]);
    store4(t + 256, v1, sc[t + 256]);
    if (t < 208) store4(t + 512, v2, sc[t + 512]);
    return;
  }
  b -= NTOK;
  {
    // ---- YaRN rope table: tab[tok][d] = (cos,sin)*conc, d<32 ----
    int idx = b * 256 + t;               // 2048*32
    int tok = idx >> 5, d = idx & 31;
    const double PI = 3.14159265358979323846;
    double i = (double)d;
    double lf = log(150000.0);
    double freq = exp(lf * (i / 32.0));
    double interp = 1.0 / (32.0 * freq);
    double extrap = 1.0 / freq;
    double low  = 32.0 * log(4096.0 / (32.0 * 2.0 * PI)) / lf;
    double high = 32.0 * log(4096.0 / (2.0 * PI)) / lf;
    double ramp = (i - low) / (high - low);
    double mm = 1.0 - fmin(fmax(ramp, 0.0), 1.0);
    double invf = interp * (1.0 - mm) + extrap * mm;
    double ang = (double)tok * invf;
    double conc = 0.1 * log(32.0) + 1.0;
    tab[idx] = make_float2((float)(cos(ang) * conc), (float)(sin(ang) * conc));
  }
}

// ---------------- QKV GEMM: 2-deep pipelined, counted vmcnt ----------------
// C[2048][5120] = A[2048][2880] * Bt[5120][2880]^T, fused bias + YaRN RoPE.
// BM=128 x BN=320 tile -> grid 16x16 = 256 blocks = exactly 1 block/CU.
// 512 thr = 8 waves (2M x 4N), wave tile 64x80, acc 4x5 frags, BK=64.
// LDS 112 KB: A dbuf 2x16KB @0, B dbuf 2x40KB @32768. Chunk-XOR swizzle
// (phys16B = logical ^ (row&7)) via pre-swizzled global source (T2).
// Pipeline per K-tile: vmcnt(7) -> barrier -> 18x ds_read_b128 ->
//   20 MFMA ks0 -> lgkmcnt(0) -> barrier -> STAGE(t+2) -> 20 MFMA ks1.
// vmcnt never drained to 0 in steady state (T4); setprio around MFMA (T5).
// Epilogue: acc -> f32 LDS stash (2 chunks of 64 rows, stride 324) ->
//   rotate pairs (d, d+32) per 64-col head -> f16 out. BN=320 = 5 heads,
//   so rope pairs are block-local even though 80-wide wave spans break
//   in-register pairing.
#define QBM 128
#define QBN 320

__global__ __launch_bounds__(512, 2) void qkv8_kernel(const _Float16* __restrict__ A,
                                                      const _Float16* __restrict__ Bt,
                                                      const float* __restrict__ bias,
                                                      const float2* __restrict__ tab,
                                                      _Float16* __restrict__ out,
                                                      int K) {
  extern __shared__ char smem[];
  int tid = threadIdx.x;
  int wave = tid >> 6, lane = tid & 63;
  int wm = wave >> 2, wn = wave & 3;
  int c = lane & 15, quad = lane >> 4;
  int n0 = blockIdx.x * QBN, m0 = blockIdx.y * QBM;
  int NT = K >> 6;                       // 45 K-tiles of 64

  // staging pointers: source pre-swizzled so linear LDS dest = swizzled layout
  const _Float16* gA[2];
  #pragma unroll
  for (int i = 0; i < 2; ++i) {
    int ci = i * 512 + tid, r = ci >> 3, lc = (ci & 7) ^ (r & 7);
    gA[i] = A + (size_t)(m0 + r) * K + lc * 8;
  }
  const _Float16* gB[5];
  #pragma unroll
  for (int i = 0; i < 5; ++i) {
    int ci = i * 512 + tid, r = ci >> 3, lc = (ci & 7) ^ (r & 7);
    gB[i] = Bt + (size_t)(n0 + r) * K + lc * 8;
  }
  char* lA = smem + (size_t)(wave * 64) * 16;          // wave-uniform bases
  char* lB = smem + 32768 + (size_t)(wave * 64) * 16;

  auto STAGE = [&](int sel, int t) {
    size_t ko = (size_t)t * 64;
    #pragma unroll
    for (int i = 0; i < 2; ++i) gload16(gA[i] + ko, lA + sel * 16384 + i * 8192);
    #pragma unroll
    for (int i = 0; i < 5; ++i) gload16(gB[i] + ko, lB + sel * 40960 + i * 8192);
  };

  // ds_read byte offsets (swizzled chunk = (ks*4+quad) ^ (c&7))
  int aoff[2], boff[2];
  #pragma unroll
  for (int ks = 0; ks < 2; ++ks) {
    int px = ((ks * 4 + quad) ^ (c & 7)) * 16;
    aoff[ks] = (wm * 64 + c) * 128 + px;
    boff[ks] = (wn * 80 + c) * 128 + px;
  }

  f32x4 acc[4][5] = {};
  STAGE(0, 0);
  STAGE(1, 1);

  #pragma unroll 1
  for (int t = 0; t < NT; ++t) {
    if (t + 1 < NT) asm volatile("s_waitcnt vmcnt(7)" ::: "memory");
    else            asm volatile("s_waitcnt vmcnt(0)" ::: "memory");
    __builtin_amdgcn_s_barrier();
    asm volatile("" ::: "memory");
    const char* Ab = smem + (t & 1) * 16384;
    const char* Bb = smem + 32768 + (t & 1) * 40960;
    half8 a[4][2], b[5][2];
    #pragma unroll
    for (int i = 0; i < 4; ++i) {
      a[i][0] = *(const half8*)(Ab + aoff[0] + i * 2048);
      a[i][1] = *(const half8*)(Ab + aoff[1] + i * 2048);
    }
    #pragma unroll
    for (int j = 0; j < 5; ++j) {
      b[j][0] = *(const half8*)(Bb + boff[0] + j * 2048);
      b[j][1] = *(const half8*)(Bb + boff[1] + j * 2048);
    }
    __builtin_amdgcn_s_setprio(1);
    #pragma unroll
    for (int j = 0; j < 5; ++j)
      #pragma unroll
      for (int i = 0; i < 4; ++i)
        acc[i][j] = __builtin_amdgcn_mfma_f32_16x16x32_f16(a[i][0], b[j][0], acc[i][j], 0, 0, 0);
    __builtin_amdgcn_s_setprio(0);
    asm volatile("s_waitcnt lgkmcnt(0)" ::: "memory");   // all 18 reads landed
    __builtin_amdgcn_s_barrier();                        // all waves done reading buf
    asm volatile("" ::: "memory");
    if (t + 2 < NT) STAGE(t & 1, t + 2);                 // overwrite read buffer
    __builtin_amdgcn_s_setprio(1);
    #pragma unroll
    for (int j = 0; j < 5; ++j)
      #pragma unroll
      for (int i = 0; i < 4; ++i)
        acc[i][j] = __builtin_amdgcn_mfma_f32_16x16x32_f16(a[i][1], b[j][1], acc[i][j], 0, 0, 0);
    __builtin_amdgcn_s_setprio(0);
  }

  // ---- epilogue: stash f32 to LDS per 64-row chunk, rotate head-local pairs ----
  asm volatile("s_waitcnt lgkmcnt(0)" ::: "memory");
  __builtin_amdgcn_s_barrier();
  asm volatile("" ::: "memory");
  float* fP = (float*)smem;              // [64][324] f32, 83 KB
  #pragma unroll
  for (int h = 0; h < 2; ++h) {
    if (wm == h) {
      #pragma unroll
      for (int j = 0; j < 5; ++j) {
        int coll = wn * 80 + j * 16 + c;
        float bv = bias[n0 + coll];
        #pragma unroll
        for (int i = 0; i < 4; ++i) {
          int rowl = i * 16 + quad * 4;
          #pragma unroll
          for (int r = 0; r < 4; ++r)
            fP[(rowl + r) * 324 + coll] = acc[i][j][r] + bv;
        }
      }
    }
    asm volatile("s_waitcnt lgkmcnt(0)" ::: "memory");
    __builtin_amdgcn_s_barrier();
    asm volatile("" ::: "memory");
    #pragma unroll
    for (int p = 0; p < 20; ++p) {       // 64 rows x 5 heads x 32 d = 10240 pairs
      int idx = p * 512 + tid;
      int row = idx / 160, s = idx - row * 160;
      int head = s >> 5, d = s & 31;
      int coll = head * 64 + d;
      int gcol = n0 + coll;
      int grow = m0 + h * 64 + row;
      float x1 = fP[row * 324 + coll];
      float x2 = fP[row * 324 + coll + 32];
      float2 cs = (gcol < 4608) ? tab[(size_t)grow * 32 + d] : make_float2(1.f, 0.f);
      out[(size_t)grow * QKV_N + gcol]      = f2h(x1 * cs.x - x2 * cs.y);
      out[(size_t)grow * QKV_N + gcol + 32] = f2h(x2 * cs.x + x1 * cs.y);
    }
    if (h == 0) {
      asm volatile("s_waitcnt lgkmcnt(0)" ::: "memory");
      __builtin_amdgcn_s_barrier();
      asm volatile("" ::: "memory");
    }
  }
}

// ---------------- f16 MFMA GEMM (O-proj): C[M][N] = A[M][K] * Bt[N][K]^T + bias ----------------
// BM x 128 tile, BK=64, 256 thr = 4 waves (2x2), wave tile (BM/2) x 64.
// LDS chunk swizzle: physical 16B chunk = logical ^ (row&7)  -> conflict-free ds_read_b128.
template <int BM, bool QKV_MODE, int MINW>
__global__ __launch_bounds__(256, MINW) void gemm_kernel(const _Float16* __restrict__ A,
                                                         const _Float16* __restrict__ Bt,
                                                         const float* __restrict__ bias,
                                                         const float* __restrict__ resid,
                                                         const float2* __restrict__ tab,
                                                         void* __restrict__ Cout,
                                                         int M, int N, int K) {
  constexpr int MI = BM / 32;            // 16-row tiles per wave
  constexpr int NA = BM / 32;            // A gload16 per thread (BM*8/256)
  __shared__ _Float16 Alds[BM * 64];
  __shared__ _Float16 Blds[128 * 64];
  int tid = threadIdx.x;
  int wave = tid >> 6, lane = tid & 63;
  int wm = wave >> 1, wn = wave & 1;
  int c = lane & 15, quad = lane >> 4;
  int m0 = blockIdx.y * BM, n0 = blockIdx.x * 128;

  const _Float16* gAp[NA]; _Float16* lAp[NA];
  #pragma unroll
  for (int i = 0; i < NA; ++i) {
    int p = wave * 64 + i * 256 + lane;
    int r = p >> 3;
    int kl = (p & 7) ^ (r & 7);
    gAp[i] = A + (size_t)(m0 + r) * K + kl * 8;
    lAp[i] = Alds + (size_t)(wave * 64 + i * 256) * 8;
  }
  const _Float16* gBp[4]; _Float16* lBp[4];
  #pragma unroll
  for (int i = 0; i < 4; ++i) {
    int p = wave * 64 + i * 256 + lane;
    int r = p >> 3;
    int kl = (p & 7) ^ (r & 7);
    gBp[i] = Bt + (size_t)(n0 + r) * K + kl * 8;
    lBp[i] = Blds + (size_t)(wave * 64 + i * 256) * 8;
  }

  int px[2];                             // swizzled chunk offsets (in halves)
  px[0] = ((0 * 4 + quad) ^ (c & 7)) * 8;
  px[1] = ((1 * 4 + quad) ^ (c & 7)) * 8;

  f32x4 acc[MI][4] = {};
  int nIter = K >> 6;
  for (int kt = 0; kt < nIter; ++kt) {
    __syncthreads();                 // previous iter's LDS reads done
    #pragma unroll
    for (int i = 0; i < NA; ++i) { gload16(gAp[i], lAp[i]); gAp[i] += 64; }
    #pragma unroll
    for (int i = 0; i < 4; ++i)  { gload16(gBp[i], lBp[i]); gBp[i] += 64; }
    __syncthreads();                 // vmcnt drained -> tiles visible
    half8 a[MI][2], b[4][2];
    #pragma unroll
    for (int i = 0; i < MI; ++i) {
      int row = wm * (BM / 2) + i * 16 + c;
      a[i][0] = *(const half8*)&Alds[row * 64 + px[0]];
      a[i][1] = *(const half8*)&Alds[row * 64 + px[1]];
    }
    #pragma unroll
    for (int j = 0; j < 4; ++j) {
      int row = wn * 64 + j * 16 + c;
      b[j][0] = *(const half8*)&Blds[row * 64 + px[0]];
      b[j][1] = *(const half8*)&Blds[row * 64 + px[1]];
    }
    #pragma unroll
    for (int i = 0; i < MI; ++i)
      #pragma unroll
      for (int j = 0; j < 4; ++j) {
        acc[i][j] = __builtin_amdgcn_mfma_f32_16x16x32_f16(a[i][0], b[j][0], acc[i][j], 0, 0, 0);
        acc[i][j] = __builtin_amdgcn_mfma_f32_16x16x32_f16(a[i][1], b[j][1], acc[i][j], 0, 0, 0);
      }
  }

  // epilogue: C layout col=lane&15, row=quad*4+reg
  if (QKV_MODE) {
    _Float16* outp = (_Float16*)Cout;
    bool ropeTile = (n0 < 4608);
    #pragma unroll
    for (int i = 0; i < MI; ++i) {
      int rowb = m0 + wm * (BM / 2) + i * 16 + quad * 4;
      if (ropeTile) {
        #pragma unroll
        for (int jp = 0; jp < 2; ++jp) {
          int col = n0 + wn * 64 + jp * 16 + c;
          float b1 = bias[col], b2 = bias[col + 32];
          #pragma unroll
          for (int r = 0; r < 4; ++r) {
            float2 cs = tab[(size_t)(rowb + r) * 32 + jp * 16 + c];
            float x1 = acc[i][jp][r] + b1;
            float x2 = acc[i][jp + 2][r] + b2;
            outp[(size_t)(rowb + r) * QKV_N + col]      = f2h(x1 * cs.x - x2 * cs.y);
            outp[(size_t)(rowb + r) * QKV_N + col + 32] = f2h(x2 * cs.x + x1 * cs.y);
          }
        }
      } else {
        #pragma unroll
        for (int j = 0; j < 4; ++j) {
          int col = n0 + wn * 64 + j * 16 + c;
          float bv = bias[col];
          #pragma unroll
          for (int r = 0; r < 4; ++r)
            outp[(size_t)(rowb + r) * QKV_N + col] = f2h(acc[i][j][r] + bv);
        }
      }
    }
  } else {
    float* outp = (float*)Cout;
    #pragma unroll
    for (int i = 0; i < MI; ++i) {
      int rowb = m0 + wm * (BM / 2) + i * 16 + quad * 4;
      #pragma unroll
      for (int j = 0; j < 4; ++j) {
        int col = n0 + wn * 64 + j * 16 + c;
        if (col < N) {
          float bv = bias[col];
          #pragma unroll
          for (int r = 0; r < 4; ++r)
            outp[(size_t)(rowb + r) * N + col] =
                acc[i][j][r] + bv + resid[(size_t)(rowb + r) * N + col];
        }
      }
    }
  }
}

// ---------------- sliding-window GQA attention with sink ----------------
#define TQ 16
__global__ __launch_bounds__(256) void attn_kernel(const _Float16* __restrict__ qkv,
                                                   const float* __restrict__ sink,
                                                   _Float16* __restrict__ attn_out) {
  __shared__ __align__(16) char smem[61440];
  _Float16* Klds = (_Float16*)smem;             // [160 keys][64 d] swizzled, 20480 B
  _Float16* Qlds = (_Float16*)(smem + 20480);   // [16 tok][8 qm][64 d] swizzled, 16384 B
  _Float16* Ps   = (_Float16*)smem;             // [128 m][160 key] f16, 40960 B (aliases K,Q)
  _Float16* Vt   = (_Float16*)(smem + 40960);   // [64 d][160 key], 20480 B

  int qt = blockIdx.x, kvh = blockIdx.y;
  int Q0 = qt * TQ;
  int kmin = (Q0 >= WIN) ? Q0 - WIN : 0;
  int nkv = Q0 + TQ - kmin;            // valid keys (<=144)
  int tid = threadIdx.x;
  int wave = tid >> 6, lane = tid & 63;
  int c = lane & 15, quad = lane >> 4;

  {
    const _Float16* kbase = qkv + 4096 + kvh * 64;
    #pragma unroll
    for (int p = 0; p < 5; ++p) {
      int ci = p * 256 + wave * 64 + lane;
      int row = ci >> 3, pc = ci & 7;
      int lc = pc ^ (row & 7);
      gload16(kbase + (size_t)(kmin + row) * QKV_N + lc * 8,
              (char*)Klds + (size_t)(p * 256 + wave * 64) * 16);
    }
  }
  {
    const _Float16* qbase = qkv + kvh * 512;
    #pragma unroll
    for (int p = 0; p < 4; ++p) {
      int ci = p * 256 + wave * 64 + lane;
      int tok = ci >> 6, Lp = ci & 63;
      int Llog = (Lp & 56) | ((Lp ^ tok) & 7);
      gload16(qbase + (size_t)(Q0 + tok) * QKV_N + Llog * 8,
              (char*)Qlds + (size_t)(p * 256 + wave * 64) * 16);
    }
  }
  #pragma unroll
  for (int p = 0; p < 5; ++p) {
    int cc = p * 256 + tid;            // 8 d-chunks x 160 cols = 1280
    int col = cc % 160;
    int d0 = (cc / 160) * 8;
    union { uint4 u4; _Float16 hv[8]; } buf;
    if (col < nkv) buf.u4 = *(const uint4*)(qkv + (size_t)(kmin + col) * QKV_N + 4608 + kvh * 64 + d0);
    else           buf.u4 = make_uint4(0, 0, 0, 0);
    #pragma unroll
    for (int uu = 0; uu < 8; ++uu) Vt[(d0 + uu) * 160 + col] = buf.hv[uu];
  }

  __syncthreads();

  half8 aq[2][2];
  #pragma unroll
  for (int i = 0; i < 2; ++i) {
    int qm = wave * 2 + i;
    #pragma unroll
    for (int ks = 0; ks < 2; ++ks) {
      int kc = ks * 4 + quad;
      int Lp = qm * 8 + (kc ^ (c & 7));
      aq[i][ks] = *(const half8*)&Qlds[c * 512 + Lp * 8];
    }
  }

  f32x4 sacc[2][9] = {};
  #pragma unroll
  for (int j = 0; j < 9; ++j) {
    #pragma unroll
    for (int ks = 0; ks < 2; ++ks) {
      int kc = ks * 4 + quad;
      int pc = kc ^ (c & 7);
      half8 bk = *(const half8*)&Klds[(j * 16 + c) * 64 + pc * 8];
      #pragma unroll
      for (int i = 0; i < 2; ++i)
        sacc[i][j] = __builtin_amdgcn_mfma_f32_16x16x32_f16(aq[i][ks], bk, sacc[i][j], 0, 0, 0);
    }
  }

  __syncthreads();

  #pragma unroll
  for (int p = 0; p < 8; ++p) {
    int idx = p * 256 + tid;
    Ps[(idx >> 4) * 160 + 144 + (idx & 15)] = (_Float16)0.f;
  }

  #pragma unroll
  for (int i = 0; i < 2; ++i) {
    int qm = wave * 2 + i;
    float sk = sink[kvh * 8 + qm];
    #pragma unroll
    for (int r = 0; r < 4; ++r) {
      int qpos = Q0 + quad * 4 + r;
      float sv[9]; float mx = -3e38f;
      #pragma unroll
      for (int j = 0; j < 9; ++j) {
        int key = kmin + j * 16 + c;
        float s = sacc[i][j][r] * SM_SCALE;
        bool valid = (key <= qpos) && (qpos - key <= WIN);
        sv[j] = valid ? s : -3e38f;
        mx = fmaxf(mx, sv[j]);
      }
      #pragma unroll
      for (int msk = 1; msk < 16; msk <<= 1) mx = fmaxf(mx, __shfl_xor(mx, msk, 64));
      mx = fmaxf(mx, sk);
      float sum = 0.f; float pv[9];
      #pragma unroll
      for (int j = 0; j < 9; ++j) { float p = __expf(sv[j] - mx); pv[j] = p; sum += p; }
      #pragma unroll
      for (int msk = 1; msk < 16; msk <<= 1) sum += __shfl_xor(sum, msk, 64);
      sum += __expf(sk - mx);
      float inv = 1.0f / sum;
      int mrow = qm * 16 + quad * 4 + r;
      #pragma unroll
      for (int j = 0; j < 9; ++j)
        Ps[mrow * 160 + j * 16 + c] = f2h(pv[j] * inv);
    }
  }

  __syncthreads();

  f32x4 oacc[2][4] = {};
  #pragma unroll
  for (int ks = 0; ks < 5; ++ks) {
    half8 ap[2], bv[4];
    #pragma unroll
    for (int i = 0; i < 2; ++i)
      ap[i] = *(const half8*)&Ps[((wave * 2 + i) * 16 + c) * 160 + ks * 32 + quad * 8];
    #pragma unroll
    for (int j = 0; j < 4; ++j)
      bv[j] = *(const half8*)&Vt[(j * 16 + c) * 160 + ks * 32 + quad * 8];
    #pragma unroll
    for (int i = 0; i < 2; ++i)
      #pragma unroll
      for (int j = 0; j < 4; ++j)
        oacc[i][j] = __builtin_amdgcn_mfma_f32_16x16x32_f16(ap[i], bv[j], oacc[i][j], 0, 0, 0);
  }

  #pragma unroll
  for (int i = 0; i < 2; ++i) {
    int qm = wave * 2 + i;
    #pragma unroll
    for (int j = 0; j < 4; ++j)
      #pragma unroll
      for (int r = 0; r < 4; ++r) {
        int token = Q0 + quad * 4 + r;
        attn_out[(size_t)token * 4096 + (kvh * 8 + qm) * 64 + j * 16 + c] = f2h(oacc[i][j][r]);
      }
  }
}

// ---------------- launch ----------------
extern "C" void kernel_launch(void* const* d_in, const int* in_sizes, int n_in,
                              void* d_out, int out_size, void* d_ws, size_t ws_size,
                              hipStream_t stream) {
  (void)in_sizes; (void)n_in; (void)out_size; (void)ws_size;
  const float* x      = (const float*)d_in[0];
  const float* scale  = (const float*)d_in[1];
  const float* sink   = (const float*)d_in[2];
  const float* w_qkv  = (const float*)d_in[3];
  const float* b_qkv  = (const float*)d_in[4];
  const float* w_o    = (const float*)d_in[5];
  const float* b_o    = (const float*)d_in[6];
  float* out = (float*)d_out;

  char* ws = (char*)d_ws;
  size_t off = 0;
  auto alloc = [&](size_t bytes) { void* p = ws + off; off += (bytes + 255) & ~(size_t)255; return p; };
  _Float16* wtq   = (_Float16*)alloc((size_t)QKV_N * HIDDEN * 2);  // 29.5 MB, dead after QKV gemm
  _Float16* wto   = (_Float16*)alloc((size_t)2944 * OPROJ_K * 2);  // 24.1 MB
  _Float16* a_h   = (_Float16*)alloc((size_t)NTOK * HIDDEN * 2);   // 11.8 MB
  _Float16* qkv_h = (_Float16*)alloc((size_t)NTOK * QKV_N * 2);    // 21.0 MB
  float2*   tab   = (float2*)alloc((size_t)NTOK * 32 * sizeof(float2)); // 0.5 MB (also K-stage OOB slack)
  _Float16* at_h  = (_Float16*)wtq;                                // 16.8 MB, aliases dead wtq

  static int qkv_attr_set = 0;
  if (!qkv_attr_set) {
    hipFuncSetAttribute((const void*)qkv8_kernel,
                        hipFuncAttributeMaxDynamicSharedMemorySize, 114688);
    qkv_attr_set = 1;
  }

  int prep_blocks = NB_T0 + NB_T1 + NTOK + NB_ROPE;   // 8848
  prep_kernel<<<prep_blocks, 256, 0, stream>>>(x, scale, w_qkv, w_o, a_h, wtq, wto, tab);
  qkv8_kernel<<<dim3(QKV_N / QBN, NTOK / QBM), 512, 114688, stream>>>(
      a_h, wtq, b_qkv, tab, qkv_h, HIDDEN);
  attn_kernel<<<dim3(NTOK / TQ, 8), 256, 0, stream>>>(qkv_h, sink, at_h);
  gemm_kernel<64, false, 4><<<dim3(23, NTOK / 64), 256, 0, stream>>>(
      at_h, wto, b_o, x, nullptr, out, NTOK, HIDDEN, OPROJ_K);
}

// Round 2
// 336.750 us; speedup vs baseline: 1.0045x; 1.0045x over previous
//
#include <hip/hip_runtime.h>
#include <cstdint>
#include <cstddef>

#define HIDDEN   2880
#define QKV_N    5120      // (64 + 2*8)*64
#define OPROJ_K  4096      // 64*64
#define NTOK     2048
#define WIN      128
#define SM_SCALE 0.125f

typedef _Float16 half8  __attribute__((ext_vector_type(8)));
typedef _Float16 half4v __attribute__((ext_vector_type(4)));
typedef float    f32x4  __attribute__((ext_vector_type(4)));

__device__ __forceinline__ void gload16(const void* g, void* l) {
  // async global->LDS, 16B per lane; LDS dest = wave-uniform base + lane*16
  __builtin_amdgcn_global_load_lds((__attribute__((address_space(1))) void*)g,
                                   (__attribute__((address_space(3))) void*)l,
                                   16, 0, 0);
}

__device__ __forceinline__ _Float16 f2h(float f) { return (_Float16)f; }

// ================= merged prep kernel =================
// blocks [0, NB_T0)      : cast+transpose w_qkv -> wtq[5120][2880] f16 (64x64 tiles)
// blocks [.., +NB_T1)    : cast+transpose w_o   -> wto[2944][4096] f16 (rows>=2880 zero)
// blocks [.., +NTOK)     : rmsnorm row
// blocks [.., +NB_ROPE)  : YaRN rope table
#define NB_T0  (80 * 45)
#define NB_T1  (46 * 64)
#define NB_ROPE 256

__device__ __forceinline__ void cast_transpose64(const float* __restrict__ W,
                                                 _Float16* __restrict__ Wt,
                                                 int K, int N, int n0, int k0,
                                                 float* tile /*64x65*/) {
  int t = threadIdx.x;
  #pragma unroll
  for (int p = 0; p < 16; ++p) {
    int r = p * 4 + (t >> 6), cc = t & 63;     // r = k-local, cc = n-local
    float vv = 0.f;
    if (n0 + cc < N) vv = W[(size_t)(k0 + r) * N + n0 + cc];
    tile[r * 65 + cc] = vv;
  }
  __syncthreads();
  #pragma unroll
  for (int p = 0; p < 2; ++p) {
    int idx = p * 256 + t;
    int r = idx >> 3, ch = (idx & 7) * 8;      // r = n-local, ch = k-local
    half8 h;
    #pragma unroll
    for (int u = 0; u < 8; ++u) h[u] = (_Float16)tile[(ch + u) * 65 + r];
    *(half8*)&Wt[(size_t)(n0 + r) * K + k0 + ch] = h;
  }
}

__global__ __launch_bounds__(256) void prep_kernel(const float* __restrict__ x,
                                                   const float* __restrict__ scale,
                                                   const float* __restrict__ w_qkv,
                                                   const float* __restrict__ w_o,
                                                   _Float16* __restrict__ a_h,
                                                   _Float16* __restrict__ wtq,
                                                   _Float16* __restrict__ wto,
                                                   float2* __restrict__ tab) {
  __shared__ float smem[64 * 65];
  int b = blockIdx.x, t = threadIdx.x;
  if (b < NB_T0) {
    cast_transpose64(w_qkv, wtq, HIDDEN, QKV_N, (b % 80) * 64, (b / 80) * 64, smem);
    return;
  }
  b -= NB_T0;
  if (b < NB_T1) {
    cast_transpose64(w_o, wto, OPROJ_K, HIDDEN, (b % 46) * 64, (b / 46) * 64, smem);
    return;
  }
  b -= NB_T1;
  if (b < NTOK) {
    // ---- RMSNorm row b: fp32 -> f16 normalized*scale ----
    int row = b;
    const float4* xr = (const float4*)(x + (size_t)row * HIDDEN);
    const float4* sc = (const float4*)scale;
    float4 v0 = xr[t];
    float4 v1 = xr[t + 256];
    float4 v2 = (t < 208) ? xr[t + 512] : make_float4(0.f, 0.f, 0.f, 0.f);
    float ss = v0.x*v0.x + v0.y*v0.y + v0.z*v0.z + v0.w*v0.w
             + v1.x*v1.x + v1.y*v1.y + v1.z*v1.z + v1.w*v1.w
             + v2.x*v2.x + v2.y*v2.y + v2.z*v2.z + v2.w*v2.w;
    #pragma unroll
    for (int m = 1; m < 64; m <<= 1) ss += __shfl_xor(ss, m, 64);
    if ((t & 63) == 0) smem[t >> 6] = ss;
    __syncthreads();
    float inv = 1.0f / sqrtf((smem[0] + smem[1] + smem[2] + smem[3]) * (1.0f / HIDDEN) + 1e-5f);
    _Float16* orow = a_h + (size_t)row * HIDDEN;
    auto store4 = [&](int c4, const float4& v, const float4& s) {
      half4v h;
      h[0] = f2h(v.x * inv * s.x); h[1] = f2h(v.y * inv * s.y);
      h[2] = f2h(v.z * inv * s.z); h[3] = f2h(v.w * inv * s.w);
      *(half4v*)(orow + (size_t)c4 * 4) = h;
    };
    store4(t, v0, sc[t]);
    store4(t + 256, v1, sc[t + 256]);
    if (t < 208) store4(t + 512, v2, sc[t + 512]);
    return;
  }
  b -= NTOK;
  {
    // ---- YaRN rope table: tab[tok][d] = (cos,sin)*conc, d<32 ----
    int idx = b * 256 + t;               // 2048*32
    int tok = idx >> 5, d = idx & 31;
    const double PI = 3.14159265358979323846;
    double i = (double)d;
    double lf = log(150000.0);
    double freq = exp(lf * (i / 32.0));
    double interp = 1.0 / (32.0 * freq);
    double extrap = 1.0 / freq;
    double low  = 32.0 * log(4096.0 / (32.0 * 2.0 * PI)) / lf;
    double high = 32.0 * log(4096.0 / (2.0 * PI)) / lf;
    double ramp = (i - low) / (high - low);
    double mm = 1.0 - fmin(fmax(ramp, 0.0), 1.0);
    double invf = interp * (1.0 - mm) + extrap * mm;
    double ang = (double)tok * invf;
    double conc = 0.1 * log(32.0) + 1.0;
    tab[idx] = make_float2((float)(cos(ang) * conc), (float)(sin(ang) * conc));
  }
}

// ---------------- QKV GEMM: interleaved-phase pipelined, counted vmcnt ----------------
// C[2048][5120] = A[2048][2880] * Bt[5120][2880]^T, fused bias + YaRN RoPE.
// BM=128 x BN=320 tile -> grid 16x16 = 256 blocks = exactly 1 block/CU.
// 512 thr = 8 waves (2M x 4N), wave tile 64x80, acc 4x5 frags, BK=64.
// LDS 112 KB: A dbuf 2x16KB @0, B dbuf 2x40KB @32768. Chunk-XOR swizzle
// (phys16B = logical ^ (row&7)) via pre-swizzled global source (T2).
//
// K-loop body (per 64-K tile), read/MFMA interleave pinned by sched_barrier(0):
//   vmcnt(7) -> barrier
//   R1{a01@k0,b0..4@k0} R2{a23@k0} | C0{mi01*nj,k0} | R3{a01,b@k1} |
//   C1{mi23,k0} | R4{a23@k1} | C2{mi01,k1} | C3{mi23,k1}
//   barrier -> STAGE(t+2)
// Reads are plain loads -> compiler emits exact counted lgkmcnt before each
// cluster; sched_barrier(0) only pins the interleave so the LDS port serves
// batch p+1 while MFMA cluster p executes. vmcnt never drained in-loop (T4);
// setprio around each MFMA cluster (T5).
#define QBM 128
#define QBN 320

__global__ __launch_bounds__(512, 2) void qkv8_kernel(const _Float16* __restrict__ A,
                                                      const _Float16* __restrict__ Bt,
                                                      const float* __restrict__ bias,
                                                      const float2* __restrict__ tab,
                                                      _Float16* __restrict__ out,
                                                      int K) {
  extern __shared__ char smem[];
  int tid = threadIdx.x;
  int wave = tid >> 6, lane = tid & 63;
  int wm = wave >> 2, wn = wave & 3;
  int c = lane & 15, quad = lane >> 4;
  int n0 = blockIdx.x * QBN, m0 = blockIdx.y * QBM;
  int NT = K >> 6;                       // 45 K-tiles of 64

  // staging pointers: source pre-swizzled so linear LDS dest = swizzled layout
  const _Float16* gA[2];
  #pragma unroll
  for (int i = 0; i < 2; ++i) {
    int ci = i * 512 + tid, r = ci >> 3, lc = (ci & 7) ^ (r & 7);
    gA[i] = A + (size_t)(m0 + r) * K + lc * 8;
  }
  const _Float16* gB[5];
  #pragma unroll
  for (int i = 0; i < 5; ++i) {
    int ci = i * 512 + tid, r = ci >> 3, lc = (ci & 7) ^ (r & 7);
    gB[i] = Bt + (size_t)(n0 + r) * K + lc * 8;
  }
  char* lA = smem + (size_t)(wave * 64) * 16;          // wave-uniform bases
  char* lB = smem + 32768 + (size_t)(wave * 64) * 16;

  auto STAGE = [&](int sel, int t) {
    size_t ko = (size_t)t * 64;
    #pragma unroll
    for (int i = 0; i < 2; ++i) gload16(gA[i] + ko, lA + sel * 16384 + i * 8192);
    #pragma unroll
    for (int i = 0; i < 5; ++i) gload16(gB[i] + ko, lB + sel * 40960 + i * 8192);
  };

  // ds_read byte offsets (swizzled chunk = (ks*4+quad) ^ (c&7))
  int aoff[2], boff[2];
  #pragma unroll
  for (int ks = 0; ks < 2; ++ks) {
    int px = ((ks * 4 + quad) ^ (c & 7)) * 16;
    aoff[ks] = (wm * 64 + c) * 128 + px;
    boff[ks] = (wn * 80 + c) * 128 + px;
  }

  f32x4 acc[4][5] = {};
  STAGE(0, 0);
  STAGE(1, 1);

  #pragma unroll 1
  for (int t = 0; t < NT; ++t) {
    if (t + 1 < NT) asm volatile("s_waitcnt vmcnt(7)" ::: "memory");
    else            asm volatile("s_waitcnt vmcnt(0)" ::: "memory");
    __builtin_amdgcn_s_barrier();
    asm volatile("" ::: "memory");
    const char* Ab = smem + (t & 1) * 16384;
    const char* Bb = smem + 32768 + (t & 1) * 40960;
    half8 a[4][2], b[5][2];
    // R1: a01 @ks0 + b @ks0 (7 reads)
    a[0][0] = *(const half8*)(Ab + aoff[0] + 0 * 2048);
    a[1][0] = *(const half8*)(Ab + aoff[0] + 1 * 2048);
    #pragma unroll
    for (int j = 0; j < 5; ++j) b[j][0] = *(const half8*)(Bb + boff[0] + j * 2048);
    // R2: a23 @ks0 (2 reads)
    a[2][0] = *(const half8*)(Ab + aoff[0] + 2 * 2048);
    a[3][0] = *(const half8*)(Ab + aoff[0] + 3 * 2048);
    __builtin_amdgcn_sched_barrier(0);
    // C0: mi01 x nj @ks0 (10 MFMA) — waits only R1
    __builtin_amdgcn_s_setprio(1);
    #pragma unroll
    for (int j = 0; j < 5; ++j) {
      acc[0][j] = __builtin_amdgcn_mfma_f32_16x16x32_f16(a[0][0], b[j][0], acc[0][j], 0, 0, 0);
      acc[1][j] = __builtin_amdgcn_mfma_f32_16x16x32_f16(a[1][0], b[j][0], acc[1][j], 0, 0, 0);
    }
    __builtin_amdgcn_s_setprio(0);
    __builtin_amdgcn_sched_barrier(0);
    // R3: a01 @ks1 + b @ks1 (7 reads) — overlaps C1
    a[0][1] = *(const half8*)(Ab + aoff[1] + 0 * 2048);
    a[1][1] = *(const half8*)(Ab + aoff[1] + 1 * 2048);
    #pragma unroll
    for (int j = 0; j < 5; ++j) b[j][1] = *(const half8*)(Bb + boff[1] + j * 2048);
    __builtin_amdgcn_sched_barrier(0);
    // C1: mi23 x nj @ks0 (10 MFMA) — waits R2
    __builtin_amdgcn_s_setprio(1);
    #pragma unroll
    for (int j = 0; j < 5; ++j) {
      acc[2][j] = __builtin_amdgcn_mfma_f32_16x16x32_f16(a[2][0], b[j][0], acc[2][j], 0, 0, 0);
      acc[3][j] = __builtin_amdgcn_mfma_f32_16x16x32_f16(a[3][0], b[j][0], acc[3][j], 0, 0, 0);
    }
    __builtin_amdgcn_s_setprio(0);
    __builtin_amdgcn_sched_barrier(0);
    // R4: a23 @ks1 (2 reads) — overlaps C2
    a[2][1] = *(const half8*)(Ab + aoff[1] + 2 * 2048);
    a[3][1] = *(const half8*)(Ab + aoff[1] + 3 * 2048);
    __builtin_amdgcn_sched_barrier(0);
    // C2: mi01 x nj @ks1 (10 MFMA) — waits R3
    __builtin_amdgcn_s_setprio(1);
    #pragma unroll
    for (int j = 0; j < 5; ++j) {
      acc[0][j] = __builtin_amdgcn_mfma_f32_16x16x32_f16(a[0][1], b[j][1], acc[0][j], 0, 0, 0);
      acc[1][j] = __builtin_amdgcn_mfma_f32_16x16x32_f16(a[1][1], b[j][1], acc[1][j], 0, 0, 0);
    }
    __builtin_amdgcn_s_setprio(0);
    __builtin_amdgcn_sched_barrier(0);
    // C3: mi23 x nj @ks1 (10 MFMA) — waits R4; after this all 18 reads landed
    __builtin_amdgcn_s_setprio(1);
    #pragma unroll
    for (int j = 0; j < 5; ++j) {
      acc[2][j] = __builtin_amdgcn_mfma_f32_16x16x32_f16(a[2][1], b[j][1], acc[2][j], 0, 0, 0);
      acc[3][j] = __builtin_amdgcn_mfma_f32_16x16x32_f16(a[3][1], b[j][1], acc[3][j], 0, 0, 0);
    }
    __builtin_amdgcn_s_setprio(0);
    asm volatile("" ::: "memory");
    __builtin_amdgcn_s_barrier();        // all waves' reads landed -> buf reusable
    asm volatile("" ::: "memory");
    if (t + 2 < NT) STAGE(t & 1, t + 2);
  }

  // ---- epilogue: stash f32 to LDS per 64-row chunk, rotate head-local pairs ----
  asm volatile("s_waitcnt lgkmcnt(0)" ::: "memory");
  __builtin_amdgcn_s_barrier();
  asm volatile("" ::: "memory");
  float* fP = (float*)smem;              // [64][324] f32, 83 KB
  #pragma unroll
  for (int h = 0; h < 2; ++h) {
    if (wm == h) {
      #pragma unroll
      for (int j = 0; j < 5; ++j) {
        int coll = wn * 80 + j * 16 + c;
        float bv = bias[n0 + coll];
        #pragma unroll
        for (int i = 0; i < 4; ++i) {
          int rowl = i * 16 + quad * 4;
          #pragma unroll
          for (int r = 0; r < 4; ++r)
            fP[(rowl + r) * 324 + coll] = acc[i][j][r] + bv;
        }
      }
    }
    asm volatile("s_waitcnt lgkmcnt(0)" ::: "memory");
    __builtin_amdgcn_s_barrier();
    asm volatile("" ::: "memory");
    #pragma unroll
    for (int p = 0; p < 20; ++p) {       // 64 rows x 5 heads x 32 d = 10240 pairs
      int idx = p * 512 + tid;
      int row = idx / 160, s = idx - row * 160;
      int head = s >> 5, d = s & 31;
      int coll = head * 64 + d;
      int gcol = n0 + coll;
      int grow = m0 + h * 64 + row;
      float x1 = fP[row * 324 + coll];
      float x2 = fP[row * 324 + coll + 32];
      float2 cs = (gcol < 4608) ? tab[(size_t)grow * 32 + d] : make_float2(1.f, 0.f);
      out[(size_t)grow * QKV_N + gcol]      = f2h(x1 * cs.x - x2 * cs.y);
      out[(size_t)grow * QKV_N + gcol + 32] = f2h(x2 * cs.x + x1 * cs.y);
    }
    if (h == 0) {
      asm volatile("s_waitcnt lgkmcnt(0)" ::: "memory");
      __builtin_amdgcn_s_barrier();
      asm volatile("" ::: "memory");
    }
  }
}

// ---------------- f16 MFMA GEMM (O-proj): C[M][N] = A[M][K] * Bt[N][K]^T + bias ----------------
// BM x 128 tile, BK=64, 256 thr = 4 waves (2x2), wave tile (BM/2) x 64.
// LDS chunk swizzle: physical 16B chunk = logical ^ (row&7)  -> conflict-free ds_read_b128.
template <int BM, bool QKV_MODE, int MINW>
__global__ __launch_bounds__(256, MINW) void gemm_kernel(const _Float16* __restrict__ A,
                                                         const _Float16* __restrict__ Bt,
                                                         const float* __restrict__ bias,
                                                         const float* __restrict__ resid,
                                                         const float2* __restrict__ tab,
                                                         void* __restrict__ Cout,
                                                         int M, int N, int K) {
  constexpr int MI = BM / 32;            // 16-row tiles per wave
  constexpr int NA = BM / 32;            // A gload16 per thread (BM*8/256)
  __shared__ _Float16 Alds[BM * 64];
  __shared__ _Float16 Blds[128 * 64];
  int tid = threadIdx.x;
  int wave = tid >> 6, lane = tid & 63;
  int wm = wave >> 1, wn = wave & 1;
  int c = lane & 15, quad = lane >> 4;
  int m0 = blockIdx.y * BM, n0 = blockIdx.x * 128;

  const _Float16* gAp[NA]; _Float16* lAp[NA];
  #pragma unroll
  for (int i = 0; i < NA; ++i) {
    int p = wave * 64 + i * 256 + lane;
    int r = p >> 3;
    int kl = (p & 7) ^ (r & 7);
    gAp[i] = A + (size_t)(m0 + r) * K + kl * 8;
    lAp[i] = Alds + (size_t)(wave * 64 + i * 256) * 8;
  }
  const _Float16* gBp[4]; _Float16* lBp[4];
  #pragma unroll
  for (int i = 0; i < 4; ++i) {
    int p = wave * 64 + i * 256 + lane;
    int r = p >> 3;
    int kl = (p & 7) ^ (r & 7);
    gBp[i] = Bt + (size_t)(n0 + r) * K + kl * 8;
    lBp[i] = Blds + (size_t)(wave * 64 + i * 256) * 8;
  }

  int px[2];                             // swizzled chunk offsets (in halves)
  px[0] = ((0 * 4 + quad) ^ (c & 7)) * 8;
  px[1] = ((1 * 4 + quad) ^ (c & 7)) * 8;

  f32x4 acc[MI][4] = {};
  int nIter = K >> 6;
  for (int kt = 0; kt < nIter; ++kt) {
    __syncthreads();                 // previous iter's LDS reads done
    #pragma unroll
    for (int i = 0; i < NA; ++i) { gload16(gAp[i], lAp[i]); gAp[i] += 64; }
    #pragma unroll
    for (int i = 0; i < 4; ++i)  { gload16(gBp[i], lBp[i]); gBp[i] += 64; }
    __syncthreads();                 // vmcnt drained -> tiles visible
    half8 a[MI][2], b[4][2];
    #pragma unroll
    for (int i = 0; i < MI; ++i) {
      int row = wm * (BM / 2) + i * 16 + c;
      a[i][0] = *(const half8*)&Alds[row * 64 + px[0]];
      a[i][1] = *(const half8*)&Alds[row * 64 + px[1]];
    }
    #pragma unroll
    for (int j = 0; j < 4; ++j) {
      int row = wn * 64 + j * 16 + c;
      b[j][0] = *(const half8*)&Blds[row * 64 + px[0]];
      b[j][1] = *(const half8*)&Blds[row * 64 + px[1]];
    }
    #pragma unroll
    for (int i = 0; i < MI; ++i)
      #pragma unroll
      for (int j = 0; j < 4; ++j) {
        acc[i][j] = __builtin_amdgcn_mfma_f32_16x16x32_f16(a[i][0], b[j][0], acc[i][j], 0, 0, 0);
        acc[i][j] = __builtin_amdgcn_mfma_f32_16x16x32_f16(a[i][1], b[j][1], acc[i][j], 0, 0, 0);
      }
  }

  // epilogue: C layout col=lane&15, row=quad*4+reg
  if (QKV_MODE) {
    _Float16* outp = (_Float16*)Cout;
    bool ropeTile = (n0 < 4608);
    #pragma unroll
    for (int i = 0; i < MI; ++i) {
      int rowb = m0 + wm * (BM / 2) + i * 16 + quad * 4;
      if (ropeTile) {
        #pragma unroll
        for (int jp = 0; jp < 2; ++jp) {
          int col = n0 + wn * 64 + jp * 16 + c;
          float b1 = bias[col], b2 = bias[col + 32];
          #pragma unroll
          for (int r = 0; r < 4; ++r) {
            float2 cs = tab[(size_t)(rowb + r) * 32 + jp * 16 + c];
            float x1 = acc[i][jp][r] + b1;
            float x2 = acc[i][jp + 2][r] + b2;
            outp[(size_t)(rowb + r) * QKV_N + col]      = f2h(x1 * cs.x - x2 * cs.y);
            outp[(size_t)(rowb + r) * QKV_N + col + 32] = f2h(x2 * cs.x + x1 * cs.y);
          }
        }
      } else {
        #pragma unroll
        for (int j = 0; j < 4; ++j) {
          int col = n0 + wn * 64 + j * 16 + c;
          float bv = bias[col];
          #pragma unroll
          for (int r = 0; r < 4; ++r)
            outp[(size_t)(rowb + r) * QKV_N + col] = f2h(acc[i][j][r] + bv);
        }
      }
    }
  } else {
    float* outp = (float*)Cout;
    #pragma unroll
    for (int i = 0; i < MI; ++i) {
      int rowb = m0 + wm * (BM / 2) + i * 16 + quad * 4;
      #pragma unroll
      for (int j = 0; j < 4; ++j) {
        int col = n0 + wn * 64 + j * 16 + c;
        if (col < N) {
          float bv = bias[col];
          #pragma unroll
          for (int r = 0; r < 4; ++r)
            outp[(size_t)(rowb + r) * N + col] =
                acc[i][j][r] + bv + resid[(size_t)(rowb + r) * N + col];
        }
      }
    }
  }
}

// ---------------- sliding-window GQA attention with sink ----------------
#define TQ 16
__global__ __launch_bounds__(256) void attn_kernel(const _Float16* __restrict__ qkv,
                                                   const float* __restrict__ sink,
                                                   _Float16* __restrict__ attn_out) {
  __shared__ __align__(16) char smem[61440];
  _Float16* Klds = (_Float16*)smem;             // [160 keys][64 d] swizzled, 20480 B
  _Float16* Qlds = (_Float16*)(smem + 20480);   // [16 tok][8 qm][64 d] swizzled, 16384 B
  _Float16* Ps   = (_Float16*)smem;             // [128 m][160 key] f16, 40960 B (aliases K,Q)
  _Float16* Vt   = (_Float16*)(smem + 40960);   // [64 d][160 key], 20480 B

  int qt = blockIdx.x, kvh = blockIdx.y;
  int Q0 = qt * TQ;
  int kmin = (Q0 >= WIN) ? Q0 - WIN : 0;
  int nkv = Q0 + TQ - kmin;            // valid keys (<=144)
  int tid = threadIdx.x;
  int wave = tid >> 6, lane = tid & 63;
  int c = lane & 15, quad = lane >> 4;

  {
    const _Float16* kbase = qkv + 4096 + kvh * 64;
    #pragma unroll
    for (int p = 0; p < 5; ++p) {
      int ci = p * 256 + wave * 64 + lane;
      int row = ci >> 3, pc = ci & 7;
      int lc = pc ^ (row & 7);
      gload16(kbase + (size_t)(kmin + row) * QKV_N + lc * 8,
              (char*)Klds + (size_t)(p * 256 + wave * 64) * 16);
    }
  }
  {
    const _Float16* qbase = qkv + kvh * 512;
    #pragma unroll
    for (int p = 0; p < 4; ++p) {
      int ci = p * 256 + wave * 64 + lane;
      int tok = ci >> 6, Lp = ci & 63;
      int Llog = (Lp & 56) | ((Lp ^ tok) & 7);
      gload16(qbase + (size_t)(Q0 + tok) * QKV_N + Llog * 8,
              (char*)Qlds + (size_t)(p * 256 + wave * 64) * 16);
    }
  }
  #pragma unroll
  for (int p = 0; p < 5; ++p) {
    int cc = p * 256 + tid;            // 8 d-chunks x 160 cols = 1280
    int col = cc % 160;
    int d0 = (cc / 160) * 8;
    union { uint4 u4; _Float16 hv[8]; } buf;
    if (col < nkv) buf.u4 = *(const uint4*)(qkv + (size_t)(kmin + col) * QKV_N + 4608 + kvh * 64 + d0);
    else           buf.u4 = make_uint4(0, 0, 0, 0);
    #pragma unroll
    for (int uu = 0; uu < 8; ++uu) Vt[(d0 + uu) * 160 + col] = buf.hv[uu];
  }

  __syncthreads();

  half8 aq[2][2];
  #pragma unroll
  for (int i = 0; i < 2; ++i) {
    int qm = wave * 2 + i;
    #pragma unroll
    for (int ks = 0; ks < 2; ++ks) {
      int kc = ks * 4 + quad;
      int Lp = qm * 8 + (kc ^ (c & 7));
      aq[i][ks] = *(const half8*)&Qlds[c * 512 + Lp * 8];
    }
  }

  f32x4 sacc[2][9] = {};
  #pragma unroll
  for (int j = 0; j < 9; ++j) {
    #pragma unroll
    for (int ks = 0; ks < 2; ++ks) {
      int kc = ks * 4 + quad;
      int pc = kc ^ (c & 7);
      half8 bk = *(const half8*)&Klds[(j * 16 + c) * 64 + pc * 8];
      #pragma unroll
      for (int i = 0; i < 2; ++i)
        sacc[i][j] = __builtin_amdgcn_mfma_f32_16x16x32_f16(aq[i][ks], bk, sacc[i][j], 0, 0, 0);
    }
  }

  __syncthreads();

  #pragma unroll
  for (int p = 0; p < 8; ++p) {
    int idx = p * 256 + tid;
    Ps[(idx >> 4) * 160 + 144 + (idx & 15)] = (_Float16)0.f;
  }

  #pragma unroll
  for (int i = 0; i < 2; ++i) {
    int qm = wave * 2 + i;
    float sk = sink[kvh * 8 + qm];
    #pragma unroll
    for (int r = 0; r < 4; ++r) {
      int qpos = Q0 + quad * 4 + r;
      float sv[9]; float mx = -3e38f;
      #pragma unroll
      for (int j = 0; j < 9; ++j) {
        int key = kmin + j * 16 + c;
        float s = sacc[i][j][r] * SM_SCALE;
        bool valid = (key <= qpos) && (qpos - key <= WIN);
        sv[j] = valid ? s : -3e38f;
        mx = fmaxf(mx, sv[j]);
      }
      #pragma unroll
      for (int msk = 1; msk < 16; msk <<= 1) mx = fmaxf(mx, __shfl_xor(mx, msk, 64));
      mx = fmaxf(mx, sk);
      float sum = 0.f; float pv[9];
      #pragma unroll
      for (int j = 0; j < 9; ++j) { float p = __expf(sv[j] - mx); pv[j] = p; sum += p; }
      #pragma unroll
      for (int msk = 1; msk < 16; msk <<= 1) sum += __shfl_xor(sum, msk, 64);
      sum += __expf(sk - mx);
      float inv = 1.0f / sum;
      int mrow = qm * 16 + quad * 4 + r;
      #pragma unroll
      for (int j = 0; j < 9; ++j)
        Ps[mrow * 160 + j * 16 + c] = f2h(pv[j] * inv);
    }
  }

  __syncthreads();

  f32x4 oacc[2][4] = {};
  #pragma unroll
  for (int ks = 0; ks < 5; ++ks) {
    half8 ap[2], bv[4];
    #pragma unroll
    for (int i = 0; i < 2; ++i)
      ap[i] = *(const half8*)&Ps[((wave * 2 + i) * 16 + c) * 160 + ks * 32 + quad * 8];
    #pragma unroll
    for (int j = 0; j < 4; ++j)
      bv[j] = *(const half8*)&Vt[(j * 16 + c) * 160 + ks * 32 + quad * 8];
    #pragma unroll
    for (int i = 0; i < 2; ++i)
      #pragma unroll
      for (int j = 0; j < 4; ++j)
        oacc[i][j] = __builtin_amdgcn_mfma_f32_16x16x32_f16(ap[i], bv[j], oacc[i][j], 0, 0, 0);
  }

  #pragma unroll
  for (int i = 0; i < 2; ++i) {
    int qm = wave * 2 + i;
    #pragma unroll
    for (int j = 0; j < 4; ++j)
      #pragma unroll
      for (int r = 0; r < 4; ++r) {
        int token = Q0 + quad * 4 + r;
        attn_out[(size_t)token * 4096 + (kvh * 8 + qm) * 64 + j * 16 + c] = f2h(oacc[i][j][r]);
      }
  }
}

// ---------------- launch ----------------
extern "C" void kernel_launch(void* const* d_in, const int* in_sizes, int n_in,
                              void* d_out, int out_size, void* d_ws, size_t ws_size,
                              hipStream_t stream) {
  (void)in_sizes; (void)n_in; (void)out_size; (void)ws_size;
  const float* x      = (const float*)d_in[0];
  const float* scale  = (const float*)d_in[1];
  const float* sink   = (const float*)d_in[2];
  const float* w_qkv  = (const float*)d_in[3];
  const float* b_qkv  = (const float*)d_in[4];
  const float* w_o    = (const float*)d_in[5];
  const float* b_o    = (const float*)d_in[6];
  float* out = (float*)d_out;

  char* ws = (char*)d_ws;
  size_t off = 0;
  auto alloc = [&](size_t bytes) { void* p = ws + off; off += (bytes + 255) & ~(size_t)255; return p; };
  _Float16* wtq   = (_Float16*)alloc((size_t)QKV_N * HIDDEN * 2);  // 29.5 MB, dead after QKV gemm
  _Float16* wto   = (_Float16*)alloc((size_t)2944 * OPROJ_K * 2);  // 24.1 MB
  _Float16* a_h   = (_Float16*)alloc((size_t)NTOK * HIDDEN * 2);   // 11.8 MB
  _Float16* qkv_h = (_Float16*)alloc((size_t)NTOK * QKV_N * 2);    // 21.0 MB
  float2*   tab   = (float2*)alloc((size_t)NTOK * 32 * sizeof(float2)); // 0.5 MB (also K-stage OOB slack)
  _Float16* at_h  = (_Float16*)wtq;                                // 16.8 MB, aliases dead wtq

  static int qkv_attr_set = 0;
  if (!qkv_attr_set) {
    hipFuncSetAttribute((const void*)qkv8_kernel,
                        hipFuncAttributeMaxDynamicSharedMemorySize, 114688);
    qkv_attr_set = 1;
  }

  int prep_blocks = NB_T0 + NB_T1 + NTOK + NB_ROPE;   // 8848
  prep_kernel<<<prep_blocks, 256, 0, stream>>>(x, scale, w_qkv, w_o, a_h, wtq, wto, tab);
  qkv8_kernel<<<dim3(QKV_N / QBN, NTOK / QBM), 512, 114688, stream>>>(
      a_h, wtq, b_qkv, tab, qkv_h, HIDDEN);
  attn_kernel<<<dim3(NTOK / TQ, 8), 256, 0, stream>>>(qkv_h, sink, at_h);
  gemm_kernel<64, false, 4><<<dim3(23, NTOK / 64), 256, 0, stream>>>(
      at_h, wto, b_o, x, nullptr, out, NTOK, HIDDEN, OPROJ_K);
}